// Round 10
// baseline (260.356 us; speedup 1.0000x reference)
//
#include <hip/hip_runtime.h>

// Problem constants
#define B_  4
#define T_  2048
#define E_  1024
#define H_  16
#define D_  64
#define HD_ 1024   // H_*D_
#define BT_ 8192   // B_*T_

typedef __bf16 bf16x8 __attribute__((ext_vector_type(8)));
typedef float  f32x4  __attribute__((ext_vector_type(4)));

// native f32->bf16 (RNE)
static __device__ __forceinline__ unsigned short f2bf(float f) {
  __bf16 h = (__bf16)f;
  return __builtin_bit_cast(unsigned short, h);
}
static __device__ __forceinline__ bf16x8 ldb8(const unsigned short* p) {
  return *(const bf16x8*)p;
}

// async global->LDS, 16B per lane; LDS dest = wave-uniform base + lane*16
#define GLD_LDS16(gp, lp)                                                      \
  __builtin_amdgcn_global_load_lds(                                            \
      (const __attribute__((address_space(1))) void*)(gp),                     \
      (__attribute__((address_space(3))) void*)(lp), 16, 0, 0)

// ---------------- fused prep: x cast + weight transpose-casts ----------------
// (byte-identical to R6's passing version)
__global__ __launch_bounds__(256) void prep_k(const float* __restrict__ x,
                                              const float* __restrict__ Wq,
                                              const float* __restrict__ Wk,
                                              const float* __restrict__ Wv,
                                              const float* __restrict__ Wo,
                                              unsigned short* __restrict__ xb,
                                              unsigned short* __restrict__ wT,
                                              unsigned short* __restrict__ woT) {
  const int bid = blockIdx.x, tid = threadIdx.x;
  if (bid < 2048) {                            // ---- x cast ----
    #pragma unroll
    for (int p = 0; p < 4; ++p) {
      int i = bid * 1024 + p * 256 + tid;      // float4 index
      float4 v = ((const float4*)x)[i];
      ushort4 o;
      o.x = f2bf(v.x); o.y = f2bf(v.y); o.z = f2bf(v.z); o.w = f2bf(v.w);
      ((ushort4*)xb)[i] = o;
    }
    return;
  }
  __shared__ float tl[64 * 65];                // 64x64 tile, stride 65
  if (bid < 2816) {                            // ---- Wq/Wk/Wv transpose ----
    const int tix = bid - 2048;                // 0..767
    const int w = tix >> 8;                    // 0..2
    const int h = (tix >> 4) & 15;
    const int e0 = (tix & 15) * 64;
    const float* src = (w == 0) ? Wq : (w == 1) ? Wk : Wv;
    #pragma unroll
    for (int rr = 0; rr < 4; ++rr) {
      const int e = e0 + rr * 16 + (tid >> 4);
      const int d4 = (tid & 15) * 4;
      float4 v = *(const float4*)&src[(size_t)(h * 1024 + e) * 64 + d4];
      tl[(e - e0) * 65 + d4 + 0] = v.x;
      tl[(e - e0) * 65 + d4 + 1] = v.y;
      tl[(e - e0) * 65 + d4 + 2] = v.z;
      tl[(e - e0) * 65 + d4 + 3] = v.w;
    }
    __syncthreads();
    #pragma unroll
    for (int cc = 0; cc < 4; ++cc) {
      const int d = cc * 16 + (tid >> 4);
      const int e4 = (tid & 15) * 4;
      ushort4 o;
      o.x = f2bf(tl[(e4 + 0) * 65 + d]);
      o.y = f2bf(tl[(e4 + 1) * 65 + d]);
      o.z = f2bf(tl[(e4 + 2) * 65 + d]);
      o.w = f2bf(tl[(e4 + 3) * 65 + d]);
      *(ushort4*)&wT[(size_t)((w * 16 + h) * 64 + d) * 1024 + e0 + e4] = o;
    }
    return;
  }
  {                                            // ---- Wo transpose ----
    const int tix = bid - 2816;                // 0..255
    const int hd0 = (tix >> 4) * 64;
    const int e0 = (tix & 15) * 64;
    #pragma unroll
    for (int rr = 0; rr < 4; ++rr) {
      const int hd = hd0 + rr * 16 + (tid >> 4);
      const int e4 = (tid & 15) * 4;
      float4 v = *(const float4*)&Wo[(size_t)hd * 1024 + e0 + e4];
      tl[(hd - hd0) * 65 + e4 + 0] = v.x;
      tl[(hd - hd0) * 65 + e4 + 1] = v.y;
      tl[(hd - hd0) * 65 + e4 + 2] = v.z;
      tl[(hd - hd0) * 65 + e4 + 3] = v.w;
    }
    __syncthreads();
    #pragma unroll
    for (int cc = 0; cc < 4; ++cc) {
      const int e = e0 + cc * 16 + (tid >> 4);
      const int hd4 = (tid & 15) * 4;
      ushort4 o;
      o.x = f2bf(tl[(hd4 + 0) * 65 + (e - e0)]);
      o.y = f2bf(tl[(hd4 + 1) * 65 + (e - e0)]);
      o.z = f2bf(tl[(hd4 + 2) * 65 + (e - e0)]);
      o.w = f2bf(tl[(hd4 + 3) * 65 + (e - e0)]);
      *(ushort4*)&woT[(size_t)e * 1024 + hd0 + hd4] = o;
    }
  }
}

// ------------- gemm_core32: BK=32, ring-3, counted vmcnt (qkv's best) -------
// EXACT R8/R9 version (qkv 88us, 0 conflicts). 3-buffer ring, depth-2
// prefetch, counted vmcnt(4); 64B rows, phys slot = quad ^ ((row>>1)&3);
// writer pre-swizzles global src. Buffer stride 4096 USHORTS. LDS 48 KB.
static __device__ __forceinline__ void gemm_core32(const unsigned short* __restrict__ A,
                                                   const unsigned short* __restrict__ BT,
                                                   const int K, const int m0, const int n0,
                                                   unsigned short* lA, unsigned short* lB,
                                                   f32x4 acc[4][4]) {
  const int tid  = threadIdx.x;
  const int wave = tid >> 6;
  const int lane = tid & 63;
  const int wm = wave & 1, wn = wave >> 1;
  const int l16 = lane & 15, quad = lane >> 4;
  const int nit = K >> 5;                      // K-steps of 32 (>= 3)

  const int sr = tid >> 2;
  const int sc = ((tid & 3) ^ ((sr >> 1) & 3)) * 8;   // ushorts
  const int slot = (quad ^ ((l16 >> 1) & 3)) << 3;    // ushorts

#define STG32(kt, bi) do {                                                      \
    const size_t kb = (size_t)(kt) * 32 + sc;                                   \
    unsigned short* dA = lA + (bi) * 4096 + wave * 512;                         \
    unsigned short* dB = lB + (bi) * 4096 + wave * 512;                         \
    GLD_LDS16(A  + (size_t)(m0 +      sr) * K + kb, dA);                        \
    GLD_LDS16(A  + (size_t)(m0 + 64 + sr) * K + kb, dA + 2048);                 \
    GLD_LDS16(BT + (size_t)(n0 +      sr) * K + kb, dB);                        \
    GLD_LDS16(BT + (size_t)(n0 + 64 + sr) * K + kb, dB + 2048);                 \
  } while (0)

  #pragma unroll
  for (int i = 0; i < 4; ++i)
    #pragma unroll
    for (int j = 0; j < 4; ++j) acc[i][j] = (f32x4){0.f, 0.f, 0.f, 0.f};

  STG32(0, 0);
  STG32(1, 1);
  asm volatile("s_waitcnt vmcnt(4)" ::: "memory");   // S(0) landed, S(1) in flight
  __builtin_amdgcn_s_barrier();

  int cb = 0, sb = 2;                          // current buf, stage buf (t+2)%3
  for (int it = 0; it < nit; ++it) {
    if (it + 2 < nit) STG32(it + 2, sb);       // depth-2 prefetch
    const unsigned short* cA = lA + cb * 4096;
    const unsigned short* cB = lB + cb * 4096;
    bf16x8 aF[4], bF[4];
    #pragma unroll
    for (int mi = 0; mi < 4; ++mi)
      aF[mi] = ldb8(cA + (wm * 64 + mi * 16 + l16) * 32 + slot);
    #pragma unroll
    for (int nj = 0; nj < 4; ++nj)
      bF[nj] = ldb8(cB + (wn * 64 + nj * 16 + l16) * 32 + slot);
    __builtin_amdgcn_s_setprio(1);
    #pragma unroll
    for (int mi = 0; mi < 4; ++mi)
      #pragma unroll
      for (int nj = 0; nj < 4; ++nj)
        acc[mi][nj] = __builtin_amdgcn_mfma_f32_16x16x32_bf16(aF[mi], bF[nj],
                                                              acc[mi][nj], 0, 0, 0);
    __builtin_amdgcn_s_setprio(0);
    if (it + 1 < nit) {
      if (it + 2 < nit)
        asm volatile("s_waitcnt vmcnt(4)" ::: "memory");  // S(t+1) done
      else
        asm volatile("s_waitcnt vmcnt(0)" ::: "memory");  // tail drain
      __builtin_amdgcn_s_barrier();
    }
    cb = (cb == 2) ? 0 : cb + 1;
    sb = (sb == 2) ? 0 : sb + 1;
  }
#undef STG32
}

// ------------- gemm_core64: BK=64, dbuf (proj's best, exact R6 core) --------
// R6's core (the 252.8us total). Stage(kt+1) after the barrier opening iter
// kt; implicit vmcnt(0) drain at next __syncthreads. 128B rows, reader XORs
// 16B slot with (row&7), writer pre-swizzles global src. Buffer stride 8192
// USHORTS (128x64 = 16KB). LDS 64 KB -> 2 blocks/CU.
static __device__ __forceinline__ void gemm_core64(const unsigned short* __restrict__ A,
                                                   const unsigned short* __restrict__ BT,
                                                   const int K, const int m0, const int n0,
                                                   unsigned short* lA, unsigned short* lB,
                                                   f32x4 acc[4][4]) {
  const int tid  = threadIdx.x;
  const int wave = tid >> 6;
  const int lane = tid & 63;
  const int wm = wave & 1, wn = wave >> 1;
  const int l16 = lane & 15, quad = lane >> 4;
  const int nkt = K >> 6;                      // K-tiles of 64

  const int sr = tid >> 3;                     // staging row 0..31 (per group)
  const int sc = ((tid & 7) ^ (sr & 7)) * 8;   // pre-swizzled src col (ushorts)
  const int sw = l16 & 7;                      // reader swizzle key (= row&7)
  const int sl0 = (quad ^ sw) << 3;            // ks=0 slot (ushorts)
  const int sl1 = ((4 + quad) ^ sw) << 3;      // ks=1 slot

#define STG64(kt) do {                                                          \
    const size_t kb = (size_t)(kt) * 64 + sc;                                   \
    unsigned short* dA = lA + ((kt) & 1) * 8192 + wave * 512;                   \
    unsigned short* dB = lB + ((kt) & 1) * 8192 + wave * 512;                   \
    GLD_LDS16(A  + (size_t)(m0 +      sr) * K + kb, dA);                        \
    GLD_LDS16(A  + (size_t)(m0 + 32 + sr) * K + kb, dA + 2048);                 \
    GLD_LDS16(A  + (size_t)(m0 + 64 + sr) * K + kb, dA + 4096);                 \
    GLD_LDS16(A  + (size_t)(m0 + 96 + sr) * K + kb, dA + 6144);                 \
    GLD_LDS16(BT + (size_t)(n0 +      sr) * K + kb, dB);                        \
    GLD_LDS16(BT + (size_t)(n0 + 32 + sr) * K + kb, dB + 2048);                 \
    GLD_LDS16(BT + (size_t)(n0 + 64 + sr) * K + kb, dB + 4096);                 \
    GLD_LDS16(BT + (size_t)(n0 + 96 + sr) * K + kb, dB + 6144);                 \
  } while (0)

  #pragma unroll
  for (int i = 0; i < 4; ++i)
    #pragma unroll
    for (int j = 0; j < 4; ++j) acc[i][j] = (f32x4){0.f, 0.f, 0.f, 0.f};

  STG64(0);                                    // prologue
  for (int kt = 0; kt < nkt; ++kt) {
    __syncthreads();                           // buf[kt&1] staged; prev reads done
    if (kt + 1 < nkt) STG64(kt + 1);           // prefetch; drains at next barrier
    const unsigned short* cA = lA + (kt & 1) * 8192;
    const unsigned short* cB = lB + (kt & 1) * 8192;
    bf16x8 aF[4][2], bF[4][2];
    #pragma unroll
    for (int mi = 0; mi < 4; ++mi) {
      const int ar = (wm * 64 + mi * 16 + l16) * 64;
      aF[mi][0] = ldb8(cA + ar + sl0);
      aF[mi][1] = ldb8(cA + ar + sl1);
    }
    #pragma unroll
    for (int nj = 0; nj < 4; ++nj) {
      const int br = (wn * 64 + nj * 16 + l16) * 64;
      bF[nj][0] = ldb8(cB + br + sl0);
      bF[nj][1] = ldb8(cB + br + sl1);
    }
    __builtin_amdgcn_s_setprio(1);
    #pragma unroll
    for (int mi = 0; mi < 4; ++mi)
      #pragma unroll
      for (int nj = 0; nj < 4; ++nj) {
        acc[mi][nj] = __builtin_amdgcn_mfma_f32_16x16x32_bf16(aF[mi][0], bF[nj][0],
                                                              acc[mi][nj], 0, 0, 0);
        acc[mi][nj] = __builtin_amdgcn_mfma_f32_16x16x32_bf16(aF[mi][1], bF[nj][1],
                                                              acc[mi][nj], 0, 0, 0);
      }
    __builtin_amdgcn_s_setprio(0);
  }
#undef STG64
}

// QKV: x[8192,1024] @ wT[3072,1024]^T; scatter epilogue to q/k/vT.
// q is PRE-SCALED by 0.125*log2(e) so attn can use exp2 directly.
__global__ __launch_bounds__(256) void qkv_gemm_k(const unsigned short* __restrict__ xb,
                                                  const unsigned short* __restrict__ wT,
                                                  unsigned short* __restrict__ q,
                                                  unsigned short* __restrict__ k,
                                                  unsigned short* __restrict__ vT) {
  __shared__ unsigned short lA[3 * 128 * 32], lB[3 * 128 * 32];  // 48 KB
  f32x4 acc[4][4];
  const int m0 = blockIdx.x * 128, n0 = blockIdx.y * 128;
  gemm_core32(xb, wT, E_, m0, n0, lA, lB, acc);

  const int wave = threadIdx.x >> 6, lane = threadIdx.x & 63;
  const int wm = wave & 1, wn = wave >> 1;
  const int l16 = lane & 15, quad = lane >> 4;
  const int type = n0 >> 10;                   // block-uniform
  const float C = 0.18033688011112042f;        // 0.125 * log2(e)
  #pragma unroll
  for (int i = 0; i < 4; ++i) {
    #pragma unroll
    for (int j = 0; j < 4; ++j) {
      const int n = n0 + wn * 64 + j * 16 + l16;
      const int h = (n >> 6) & 15, d = n & 63;
      #pragma unroll
      for (int r = 0; r < 4; ++r) {
        const int m = m0 + wm * 64 + i * 16 + quad * 4 + r;
        const int b = m >> 11, t = m & (T_ - 1);
        if (type == 0)
          q[((size_t)(b * H_ + h) * T_ + t) * D_ + d] = f2bf(acc[i][j][r] * C);
        else if (type == 1)
          k[((size_t)(b * H_ + h) * T_ + t) * D_ + d] = f2bf(acc[i][j][r]);
        else
          vT[((size_t)(b * H_ + h) * D_ + d) * T_ + t] = f2bf(acc[i][j][r]);
      }
    }
  }
}

// proj: ao[8192,1024] @ woT[1024,1024]^T -> out fp32 (BK=64 dbuf core, R6)
__global__ __launch_bounds__(256) void proj_k(const unsigned short* __restrict__ ao,
                                              const unsigned short* __restrict__ woT,
                                              float* __restrict__ out) {
  __shared__ unsigned short lA[2 * 128 * 64], lB[2 * 128 * 64];  // 64 KB
  f32x4 acc[4][4];
  const int m0 = blockIdx.x * 128, n0 = blockIdx.y * 128;
  gemm_core64(ao, woT, HD_, m0, n0, lA, lB, acc);

  const int wave = threadIdx.x >> 6, lane = threadIdx.x & 63;
  const int wm = wave & 1, wn = wave >> 1;
  const int l16 = lane & 15, quad = lane >> 4;
  #pragma unroll
  for (int i = 0; i < 4; ++i)
    #pragma unroll
    for (int j = 0; j < 4; ++j)
      #pragma unroll
      for (int r = 0; r < 4; ++r)
        out[(size_t)(m0 + wm * 64 + i * 16 + quad * 4 + r) * E_ +
            n0 + wn * 64 + j * 16 + l16] = acc[i][j][r];
}

// ------------- flash attention (causal, dbuf LDS staging, XCD-local) ---------
// EXACT R2/R6/R9 version (passed four times).
__global__ __launch_bounds__(256) void attn_k(const unsigned short* __restrict__ q,
                                              const unsigned short* __restrict__ k,
                                              const unsigned short* __restrict__ vT,
                                              unsigned short* __restrict__ ao) {
  __shared__ unsigned short lK[2][64 * 64];    // [s][d] seg-swizzled, 2 x 8 KB
  __shared__ unsigned short lV[2][64 * 64];    // [d][s] seg-swizzled, 2 x 8 KB
  __shared__ unsigned short lP[4][32][72];     // per-wave P tiles, padded, 18 KB
  const int tid  = threadIdx.x;
  const int lane = tid & 63;
  const int wave = tid >> 6;
  const int l16  = lane & 15;
  const int quad = lane >> 4;
  const int id    = (int)blockIdx.x;           // 0..511
  const int bhid  = id & 63;                   // same bh -> same id%8 -> same XCD
  const int qpair = id >> 6;                   // 0..7
  const int h = bhid & 15, b = bhid >> 4;
  const size_t bh = (size_t)(b * H_ + h);
  const unsigned short* qp = q  + bh * (T_ * D_);
  const unsigned short* kp = k  + bh * (T_ * D_);
  const unsigned short* vp = vT + bh * (D_ * T_);

  // staging: slot t -> (row = t/8, seg = t%8) of a 64-row x 128B tile half
  const int srow = tid >> 3;
  const int kseg = (tid & 7) ^ (srow & 7);     // XOR swizzle
  const int sw = (l16 & 7);                    // reader-side swizzle key

  #pragma unroll
  for (int pr = 0; pr < 2; ++pr) {
    const int qblk = (pr == 0) ? qpair : 15 - qpair;
    const int q0 = qblk * 128 + wave * 32;     // this wave's first q-row

    bf16x8 aq[2][2];
    #pragma unroll
    for (int rb = 0; rb < 2; ++rb)
      #pragma unroll
      for (int hh = 0; hh < 2; ++hh)
        aq[rb][hh] = ldb8(qp + (q0 + rb * 16 + l16) * D_ + hh * 32 + quad * 8);

    float lr[2][4];
    f32x4 o[2][4];
    #pragma unroll
    for (int rb = 0; rb < 2; ++rb) {
      #pragma unroll
      for (int r = 0; r < 4; ++r) lr[rb][r] = 0.f;
      #pragma unroll
      for (int nb = 0; nb < 4; ++nb) o[rb][nb] = (f32x4){0.f, 0.f, 0.f, 0.f};
    }

    const int nch = 2 * (qblk + 1);            // even

    // prologue: stage chunk 0 into buf 0
    {
      unsigned short* Kb = lK[0];
      unsigned short* Vb = lV[0];
      GLD_LDS16(kp + srow * D_ + kseg * 8, Kb + wave * 512);
      GLD_LDS16(kp + (32 + srow) * D_ + kseg * 8, Kb + 2048 + wave * 512);
      GLD_LDS16(vp + (size_t)srow * T_ + kseg * 8, Vb + wave * 512);
      GLD_LDS16(vp + (size_t)(32 + srow) * T_ + kseg * 8, Vb + 2048 + wave * 512);
    }

    for (int c = 0; c < nch; ++c) {
      __syncthreads();                         // buf[c&1] staged; prev compute done
      if (c + 1 < nch) {                       // prefetch next chunk into other buf
        const int s1 = (c + 1) * 64;
        unsigned short* Kb = lK[(c + 1) & 1];
        unsigned short* Vb = lV[(c + 1) & 1];
        GLD_LDS16(kp + (s1 + srow) * D_ + kseg * 8, Kb + wave * 512);
        GLD_LDS16(kp + (s1 + 32 + srow) * D_ + kseg * 8, Kb + 2048 + wave * 512);
        GLD_LDS16(vp + (size_t)srow * T_ + s1 + kseg * 8, Vb + wave * 512);
        GLD_LDS16(vp + (size_t)(32 + srow) * T_ + s1 + kseg * 8, Vb + 2048 + wave * 512);
      }
      const int s0 = c * 64;
      const unsigned short* Kb = lK[c & 1];
      const unsigned short* Vb = lV[c & 1];
      // ---- QK^T ----
      f32x4 sc[2][4];
      #pragma unroll
      for (int rb = 0; rb < 2; ++rb)
        #pragma unroll
        for (int j = 0; j < 4; ++j) sc[rb][j] = (f32x4){0.f, 0.f, 0.f, 0.f};
      #pragma unroll
      for (int j = 0; j < 4; ++j) {
        const int sr = j * 16 + l16;
        bf16x8 bk0 = ldb8(Kb + sr * 64 + ((quad ^ sw) << 3));
        bf16x8 bk1 = ldb8(Kb + sr * 64 + (((4 + quad) ^ sw) << 3));
        #pragma unroll
        for (int rb = 0; rb < 2; ++rb) {
          sc[rb][j] = __builtin_amdgcn_mfma_f32_16x16x32_bf16(aq[rb][0], bk0, sc[rb][j], 0, 0, 0);
          sc[rb][j] = __builtin_amdgcn_mfma_f32_16x16x32_bf16(aq[rb][1], bk1, sc[rb][j], 0, 0, 0);
        }
      }
      // ---- exp2 (+ causal mask on the diagonal chunk) + P write ----
      const bool domask = (c == nch - 1) || (c == nch - 2);  // s0+63 > q0 region
      #pragma unroll
      for (int rb = 0; rb < 2; ++rb) {
        #pragma unroll
        for (int j = 0; j < 4; ++j) {
          #pragma unroll
          for (int r = 0; r < 4; ++r) {
            float p = __builtin_amdgcn_exp2f(sc[rb][j][r]);
            if (domask) {
              const int qg = q0 + rb * 16 + quad * 4 + r;
              if (s0 + j * 16 + l16 > qg) p = 0.f;
            }
            lr[rb][r] += p;
            lP[wave][rb * 16 + quad * 4 + r][j * 16 + l16] = f2bf(p);
          }
        }
      }
      __builtin_amdgcn_wave_barrier();
      bf16x8 aP[2][2];
      #pragma unroll
      for (int rb = 0; rb < 2; ++rb)
        #pragma unroll
        for (int hh = 0; hh < 2; ++hh)
          aP[rb][hh] = ldb8(&lP[wave][rb * 16 + l16][hh * 32 + quad * 8]);
      __builtin_amdgcn_wave_barrier();
      // ---- PV ----
      #pragma unroll
      for (int nb = 0; nb < 4; ++nb) {
        const int d = nb * 16 + l16;
        bf16x8 bV0 = ldb8(Vb + d * 64 + ((quad ^ sw) << 3));
        bf16x8 bV1 = ldb8(Vb + d * 64 + (((4 + quad) ^ sw) << 3));
        #pragma unroll
        for (int rb = 0; rb < 2; ++rb) {
          o[rb][nb] = __builtin_amdgcn_mfma_f32_16x16x32_bf16(aP[rb][0], bV0, o[rb][nb], 0, 0, 0);
          o[rb][nb] = __builtin_amdgcn_mfma_f32_16x16x32_bf16(aP[rb][1], bV1, o[rb][nb], 0, 0, 0);
        }
      }
    }

    // epilogue: row-sum reduction across the 16 l16 lanes, normalize, store
    #pragma unroll
    for (int off = 1; off < 16; off <<= 1)
      #pragma unroll
      for (int rb = 0; rb < 2; ++rb)
        #pragma unroll
        for (int r = 0; r < 4; ++r)
          lr[rb][r] += __shfl_xor(lr[rb][r], off, 64);
    #pragma unroll
    for (int rb = 0; rb < 2; ++rb) {
      #pragma unroll
      for (int r = 0; r < 4; ++r) {
        const float inv = 1.0f / lr[rb][r];
        const int t = q0 + rb * 16 + quad * 4 + r;
        #pragma unroll
        for (int nb = 0; nb < 4; ++nb)
          ao[((size_t)(b * T_ + t) * H_ + h) * D_ + nb * 16 + l16] = f2bf(o[rb][nb][r] * inv);
      }
    }
  }
}

// ---------------- launch ----------------

extern "C" void kernel_launch(void* const* d_in, const int* in_sizes, int n_in,
                              void* d_out, int out_size, void* d_ws, size_t ws_size,
                              hipStream_t stream) {
  const float* x  = (const float*)d_in[0];
  const float* Wq = (const float*)d_in[1];
  const float* Wk = (const float*)d_in[2];
  const float* Wv = (const float*)d_in[3];
  const float* Wo = (const float*)d_in[4];
  float* out = (float*)d_out;

  char* ws = (char*)d_ws;
  unsigned short* xb   = (unsigned short*)(ws + 0);          // 16 MiB: x bf16 [8192,1024]
  unsigned short* wT   = (unsigned short*)(ws + 16777216);   //  6 MiB: [3,H,D,E] bf16
  unsigned short* woT  = (unsigned short*)(ws + 23068672);   //  2 MiB: [E,HD] bf16
  unsigned short* qb   = (unsigned short*)(ws + 25165824);   // 16 MiB: q [B,H,T,D] (pre-scaled)
  unsigned short* kb   = (unsigned short*)(ws + 41943040);   // 16 MiB: k [B,H,T,D]
  unsigned short* vTb  = (unsigned short*)(ws + 58720256);   // 16 MiB: v^T [B,H,D,T]
  unsigned short* aob  = (unsigned short*)(ws + 75497472);   // 16 MiB: attn out [B,T,H,D]
  // total: 92,274,688 bytes

  prep_k<<<dim3(3072), dim3(256), 0, stream>>>(x, Wq, Wk, Wv, Wo, xb, wT, woT);
  qkv_gemm_k<<<dim3(BT_ / 128, 3072 / 128), dim3(256), 0, stream>>>(xb, wT, qb, kb, vTb);
  attn_k<<<dim3(512), dim3(256), 0, stream>>>(qb, kb, vTb, aob);
  proj_k<<<dim3(BT_ / 128, E_ / 128), dim3(256), 0, stream>>>(aob, woT, out);
}

// Round 11
// 248.141 us; speedup vs baseline: 1.0492x; 1.0492x over previous
//
#include <hip/hip_runtime.h>

// Problem constants
#define B_  4
#define T_  2048
#define E_  1024
#define H_  16
#define D_  64
#define HD_ 1024   // H_*D_
#define BT_ 8192   // B_*T_

typedef __bf16 bf16x8 __attribute__((ext_vector_type(8)));
typedef float  f32x4  __attribute__((ext_vector_type(4)));

// native f32->bf16 (RNE)
static __device__ __forceinline__ unsigned short f2bf(float f) {
  __bf16 h = (__bf16)f;
  return __builtin_bit_cast(unsigned short, h);
}
static __device__ __forceinline__ bf16x8 ldb8(const unsigned short* p) {
  return *(const bf16x8*)p;
}

// async global->LDS, 16B per lane; LDS dest = wave-uniform base + lane*16
#define GLD_LDS16(gp, lp)                                                      \
  __builtin_amdgcn_global_load_lds(                                            \
      (const __attribute__((address_space(1))) void*)(gp),                     \
      (__attribute__((address_space(3))) void*)(lp), 16, 0, 0)

// ---------------- fused prep: x cast + weight transpose-casts ----------------
// (byte-identical to R6's passing version)
__global__ __launch_bounds__(256) void prep_k(const float* __restrict__ x,
                                              const float* __restrict__ Wq,
                                              const float* __restrict__ Wk,
                                              const float* __restrict__ Wv,
                                              const float* __restrict__ Wo,
                                              unsigned short* __restrict__ xb,
                                              unsigned short* __restrict__ wT,
                                              unsigned short* __restrict__ woT) {
  const int bid = blockIdx.x, tid = threadIdx.x;
  if (bid < 2048) {                            // ---- x cast ----
    #pragma unroll
    for (int p = 0; p < 4; ++p) {
      int i = bid * 1024 + p * 256 + tid;      // float4 index
      float4 v = ((const float4*)x)[i];
      ushort4 o;
      o.x = f2bf(v.x); o.y = f2bf(v.y); o.z = f2bf(v.z); o.w = f2bf(v.w);
      ((ushort4*)xb)[i] = o;
    }
    return;
  }
  __shared__ float tl[64 * 65];                // 64x64 tile, stride 65
  if (bid < 2816) {                            // ---- Wq/Wk/Wv transpose ----
    const int tix = bid - 2048;                // 0..767
    const int w = tix >> 8;                    // 0..2
    const int h = (tix >> 4) & 15;
    const int e0 = (tix & 15) * 64;
    const float* src = (w == 0) ? Wq : (w == 1) ? Wk : Wv;
    #pragma unroll
    for (int rr = 0; rr < 4; ++rr) {
      const int e = e0 + rr * 16 + (tid >> 4);
      const int d4 = (tid & 15) * 4;
      float4 v = *(const float4*)&src[(size_t)(h * 1024 + e) * 64 + d4];
      tl[(e - e0) * 65 + d4 + 0] = v.x;
      tl[(e - e0) * 65 + d4 + 1] = v.y;
      tl[(e - e0) * 65 + d4 + 2] = v.z;
      tl[(e - e0) * 65 + d4 + 3] = v.w;
    }
    __syncthreads();
    #pragma unroll
    for (int cc = 0; cc < 4; ++cc) {
      const int d = cc * 16 + (tid >> 4);
      const int e4 = (tid & 15) * 4;
      ushort4 o;
      o.x = f2bf(tl[(e4 + 0) * 65 + d]);
      o.y = f2bf(tl[(e4 + 1) * 65 + d]);
      o.z = f2bf(tl[(e4 + 2) * 65 + d]);
      o.w = f2bf(tl[(e4 + 3) * 65 + d]);
      *(ushort4*)&wT[(size_t)((w * 16 + h) * 64 + d) * 1024 + e0 + e4] = o;
    }
    return;
  }
  {                                            // ---- Wo transpose ----
    const int tix = bid - 2816;                // 0..255
    const int hd0 = (tix >> 4) * 64;
    const int e0 = (tix & 15) * 64;
    #pragma unroll
    for (int rr = 0; rr < 4; ++rr) {
      const int hd = hd0 + rr * 16 + (tid >> 4);
      const int e4 = (tid & 15) * 4;
      float4 v = *(const float4*)&Wo[(size_t)hd * 1024 + e0 + e4];
      tl[(hd - hd0) * 65 + e4 + 0] = v.x;
      tl[(hd - hd0) * 65 + e4 + 1] = v.y;
      tl[(hd - hd0) * 65 + e4 + 2] = v.z;
      tl[(hd - hd0) * 65 + e4 + 3] = v.w;
    }
    __syncthreads();
    #pragma unroll
    for (int cc = 0; cc < 4; ++cc) {
      const int e = e0 + cc * 16 + (tid >> 4);
      const int hd4 = (tid & 15) * 4;
      ushort4 o;
      o.x = f2bf(tl[(hd4 + 0) * 65 + (e - e0)]);
      o.y = f2bf(tl[(hd4 + 1) * 65 + (e - e0)]);
      o.z = f2bf(tl[(hd4 + 2) * 65 + (e - e0)]);
      o.w = f2bf(tl[(hd4 + 3) * 65 + (e - e0)]);
      *(ushort4*)&woT[(size_t)e * 1024 + hd0 + hd4] = o;
    }
  }
}

// ------------- 128x128 GEMM core: BK=64, double-buffered, conflict-free -----
// EXACT R6 core (best measured TOTAL config). Stage(kt+1) after the barrier
// opening iter kt; implicit vmcnt(0) drain at next __syncthreads. 128B rows,
// reader XORs 16B slot with (row&7), writer pre-swizzles global src.
// Buffer stride 8192 USHORTS. LDS 64 KB -> 2 blocks/CU.
static __device__ __forceinline__ void gemm_core(const unsigned short* __restrict__ A,
                                                 const unsigned short* __restrict__ BT,
                                                 const int K, const int m0, const int n0,
                                                 unsigned short* lA, unsigned short* lB,
                                                 f32x4 acc[4][4]) {
  const int tid  = threadIdx.x;
  const int wave = tid >> 6;
  const int lane = tid & 63;
  const int wm = wave & 1, wn = wave >> 1;
  const int l16 = lane & 15, quad = lane >> 4;
  const int nkt = K >> 6;                      // K-tiles of 64

  const int sr = tid >> 3;                     // staging row 0..31 (per group)
  const int sc = ((tid & 7) ^ (sr & 7)) * 8;   // pre-swizzled src col (ushorts)
  const int sw = l16 & 7;                      // reader swizzle key (= row&7)
  const int sl0 = (quad ^ sw) << 3;            // ks=0 slot (ushorts)
  const int sl1 = ((4 + quad) ^ sw) << 3;      // ks=1 slot

#define STG(kt) do {                                                            \
    const size_t kb = (size_t)(kt) * 64 + sc;                                   \
    unsigned short* dA = lA + ((kt) & 1) * 8192 + wave * 512;                   \
    unsigned short* dB = lB + ((kt) & 1) * 8192 + wave * 512;                   \
    GLD_LDS16(A  + (size_t)(m0 +      sr) * K + kb, dA);                        \
    GLD_LDS16(A  + (size_t)(m0 + 32 + sr) * K + kb, dA + 2048);                 \
    GLD_LDS16(A  + (size_t)(m0 + 64 + sr) * K + kb, dA + 4096);                 \
    GLD_LDS16(A  + (size_t)(m0 + 96 + sr) * K + kb, dA + 6144);                 \
    GLD_LDS16(BT + (size_t)(n0 +      sr) * K + kb, dB);                        \
    GLD_LDS16(BT + (size_t)(n0 + 32 + sr) * K + kb, dB + 2048);                 \
    GLD_LDS16(BT + (size_t)(n0 + 64 + sr) * K + kb, dB + 4096);                 \
    GLD_LDS16(BT + (size_t)(n0 + 96 + sr) * K + kb, dB + 6144);                 \
  } while (0)

  #pragma unroll
  for (int i = 0; i < 4; ++i)
    #pragma unroll
    for (int j = 0; j < 4; ++j) acc[i][j] = (f32x4){0.f, 0.f, 0.f, 0.f};

  STG(0);                                      // prologue
  for (int kt = 0; kt < nkt; ++kt) {
    __syncthreads();                           // buf[kt&1] staged; prev reads done
    if (kt + 1 < nkt) STG(kt + 1);             // prefetch; drains at next barrier
    const unsigned short* cA = lA + (kt & 1) * 8192;
    const unsigned short* cB = lB + (kt & 1) * 8192;
    bf16x8 aF[4][2], bF[4][2];
    #pragma unroll
    for (int mi = 0; mi < 4; ++mi) {
      const int ar = (wm * 64 + mi * 16 + l16) * 64;
      aF[mi][0] = ldb8(cA + ar + sl0);
      aF[mi][1] = ldb8(cA + ar + sl1);
    }
    #pragma unroll
    for (int nj = 0; nj < 4; ++nj) {
      const int br = (wn * 64 + nj * 16 + l16) * 64;
      bF[nj][0] = ldb8(cB + br + sl0);
      bF[nj][1] = ldb8(cB + br + sl1);
    }
    __builtin_amdgcn_s_setprio(1);
    #pragma unroll
    for (int mi = 0; mi < 4; ++mi)
      #pragma unroll
      for (int nj = 0; nj < 4; ++nj) {
        acc[mi][nj] = __builtin_amdgcn_mfma_f32_16x16x32_bf16(aF[mi][0], bF[nj][0],
                                                              acc[mi][nj], 0, 0, 0);
        acc[mi][nj] = __builtin_amdgcn_mfma_f32_16x16x32_bf16(aF[mi][1], bF[nj][1],
                                                              acc[mi][nj], 0, 0, 0);
      }
    __builtin_amdgcn_s_setprio(0);
  }
#undef STG
}

// QKV: x[8192,1024] @ wT[3072,1024]^T; scatter epilogue to q/k/vT.
// q is PRE-SCALED by 0.125*log2(e) so attn can use exp2 directly.
__global__ __launch_bounds__(256) void qkv_gemm_k(const unsigned short* __restrict__ xb,
                                                  const unsigned short* __restrict__ wT,
                                                  unsigned short* __restrict__ q,
                                                  unsigned short* __restrict__ k,
                                                  unsigned short* __restrict__ vT) {
  __shared__ unsigned short lA[2 * 128 * 64], lB[2 * 128 * 64];  // 64 KB
  f32x4 acc[4][4];
  const int m0 = blockIdx.x * 128, n0 = blockIdx.y * 128;
  gemm_core(xb, wT, E_, m0, n0, lA, lB, acc);

  const int wave = threadIdx.x >> 6, lane = threadIdx.x & 63;
  const int wm = wave & 1, wn = wave >> 1;
  const int l16 = lane & 15, quad = lane >> 4;
  const int type = n0 >> 10;                   // block-uniform
  const float C = 0.18033688011112042f;        // 0.125 * log2(e)
  #pragma unroll
  for (int i = 0; i < 4; ++i) {
    #pragma unroll
    for (int j = 0; j < 4; ++j) {
      const int n = n0 + wn * 64 + j * 16 + l16;
      const int h = (n >> 6) & 15, d = n & 63;
      #pragma unroll
      for (int r = 0; r < 4; ++r) {
        const int m = m0 + wm * 64 + i * 16 + quad * 4 + r;
        const int b = m >> 11, t = m & (T_ - 1);
        if (type == 0)
          q[((size_t)(b * H_ + h) * T_ + t) * D_ + d] = f2bf(acc[i][j][r] * C);
        else if (type == 1)
          k[((size_t)(b * H_ + h) * T_ + t) * D_ + d] = f2bf(acc[i][j][r]);
        else
          vT[((size_t)(b * H_ + h) * D_ + d) * T_ + t] = f2bf(acc[i][j][r]);
      }
    }
  }
}

// proj: ao[8192,1024] @ woT[1024,1024]^T -> out fp32
__global__ __launch_bounds__(256) void proj_k(const unsigned short* __restrict__ ao,
                                              const unsigned short* __restrict__ woT,
                                              float* __restrict__ out) {
  __shared__ unsigned short lA[2 * 128 * 64], lB[2 * 128 * 64];
  f32x4 acc[4][4];
  const int m0 = blockIdx.x * 128, n0 = blockIdx.y * 128;
  gemm_core(ao, woT, HD_, m0, n0, lA, lB, acc);

  const int wave = threadIdx.x >> 6, lane = threadIdx.x & 63;
  const int wm = wave & 1, wn = wave >> 1;
  const int l16 = lane & 15, quad = lane >> 4;
  #pragma unroll
  for (int i = 0; i < 4; ++i)
    #pragma unroll
    for (int j = 0; j < 4; ++j)
      #pragma unroll
      for (int r = 0; r < 4; ++r)
        out[(size_t)(m0 + wm * 64 + i * 16 + quad * 4 + r) * E_ +
            n0 + wn * 64 + j * 16 + l16] = acc[i][j][r];
}

// ------------- flash attention (causal, dbuf, SWAPPED-MFMA P-path) ----------
// R6 structure with ONE transform: both MFMAs take swapped operand order.
// QK^T = mfma(K-frag, Q-frag) -> lane holds S^T: q = l16, s = quad*4+r.
// Consequences (all per-lane index relabelings, NO address changes to K/Q/V
// fragment loads or the lP read-back):
//  * P write becomes contiguous in r -> pack 4 bf16 -> ONE 8B store
//    (32 x ds_write_b16 -> 8 x ds_write_b64 per lane per chunk, ~2-way banks)
//  * row-sum lr is per-(rb) scalar; epilogue reduce = 2 shfl (was 32)
//  * PV = mfma(V-frag, P-frag) -> O^T: d = quad*4+r, q = l16 -> epilogue
//    packs 4 d-values into ONE 8B global store (4x fewer stores)
__global__ __launch_bounds__(256) void attn_k(const unsigned short* __restrict__ q,
                                              const unsigned short* __restrict__ k,
                                              const unsigned short* __restrict__ vT,
                                              unsigned short* __restrict__ ao) {
  __shared__ unsigned short lK[2][64 * 64];    // [s][d] seg-swizzled, 2 x 8 KB
  __shared__ unsigned short lV[2][64 * 64];    // [d][s] seg-swizzled, 2 x 8 KB
  __shared__ unsigned short lP[4][32][72];     // per-wave P tiles [q][s], padded
  const int tid  = threadIdx.x;
  const int lane = tid & 63;
  const int wave = tid >> 6;
  const int l16  = lane & 15;
  const int quad = lane >> 4;
  const int id    = (int)blockIdx.x;           // 0..511
  const int bhid  = id & 63;                   // same bh -> same id%8 -> same XCD
  const int qpair = id >> 6;                   // 0..7
  const int h = bhid & 15, b = bhid >> 4;
  const size_t bh = (size_t)(b * H_ + h);
  const unsigned short* qp = q  + bh * (T_ * D_);
  const unsigned short* kp = k  + bh * (T_ * D_);
  const unsigned short* vp = vT + bh * (D_ * T_);

  // staging: slot t -> (row = t/8, seg = t%8) of a 64-row x 128B tile half
  const int srow = tid >> 3;
  const int kseg = (tid & 7) ^ (srow & 7);     // XOR swizzle
  const int sw = (l16 & 7);                    // reader-side swizzle key

  #pragma unroll
  for (int pr = 0; pr < 2; ++pr) {
    const int qblk = (pr == 0) ? qpair : 15 - qpair;
    const int q0 = qblk * 128 + wave * 32;     // this wave's first q-row

    bf16x8 aq[2][2];                           // Q fragments (now B-operand)
    #pragma unroll
    for (int rb = 0; rb < 2; ++rb)
      #pragma unroll
      for (int hh = 0; hh < 2; ++hh)
        aq[rb][hh] = ldb8(qp + (q0 + rb * 16 + l16) * D_ + hh * 32 + quad * 8);

    float lr[2];
    f32x4 o[2][4];
    #pragma unroll
    for (int rb = 0; rb < 2; ++rb) {
      lr[rb] = 0.f;
      #pragma unroll
      for (int nb = 0; nb < 4; ++nb) o[rb][nb] = (f32x4){0.f, 0.f, 0.f, 0.f};
    }

    const int nch = 2 * (qblk + 1);            // even

    // prologue: stage chunk 0 into buf 0
    {
      unsigned short* Kb = lK[0];
      unsigned short* Vb = lV[0];
      GLD_LDS16(kp + srow * D_ + kseg * 8, Kb + wave * 512);
      GLD_LDS16(kp + (32 + srow) * D_ + kseg * 8, Kb + 2048 + wave * 512);
      GLD_LDS16(vp + (size_t)srow * T_ + kseg * 8, Vb + wave * 512);
      GLD_LDS16(vp + (size_t)(32 + srow) * T_ + kseg * 8, Vb + 2048 + wave * 512);
    }

    for (int c = 0; c < nch; ++c) {
      __syncthreads();                         // buf[c&1] staged; prev compute done
      if (c + 1 < nch) {                       // prefetch next chunk into other buf
        const int s1 = (c + 1) * 64;
        unsigned short* Kb = lK[(c + 1) & 1];
        unsigned short* Vb = lV[(c + 1) & 1];
        GLD_LDS16(kp + (s1 + srow) * D_ + kseg * 8, Kb + wave * 512);
        GLD_LDS16(kp + (s1 + 32 + srow) * D_ + kseg * 8, Kb + 2048 + wave * 512);
        GLD_LDS16(vp + (size_t)srow * T_ + s1 + kseg * 8, Vb + wave * 512);
        GLD_LDS16(vp + (size_t)(32 + srow) * T_ + s1 + kseg * 8, Vb + 2048 + wave * 512);
      }
      const int s0 = c * 64;
      const unsigned short* Kb = lK[c & 1];
      const unsigned short* Vb = lV[c & 1];
      // ---- QK^T (swapped: K as arg0) -> sc[rb][j][r] = S[q=rb*16+l16][s=j*16+quad*4+r]
      f32x4 sc[2][4];
      #pragma unroll
      for (int rb = 0; rb < 2; ++rb)
        #pragma unroll
        for (int j = 0; j < 4; ++j) sc[rb][j] = (f32x4){0.f, 0.f, 0.f, 0.f};
      #pragma unroll
      for (int j = 0; j < 4; ++j) {
        const int sr = j * 16 + l16;
        bf16x8 bk0 = ldb8(Kb + sr * 64 + ((quad ^ sw) << 3));
        bf16x8 bk1 = ldb8(Kb + sr * 64 + (((4 + quad) ^ sw) << 3));
        #pragma unroll
        for (int rb = 0; rb < 2; ++rb) {
          sc[rb][j] = __builtin_amdgcn_mfma_f32_16x16x32_bf16(bk0, aq[rb][0], sc[rb][j], 0, 0, 0);
          sc[rb][j] = __builtin_amdgcn_mfma_f32_16x16x32_bf16(bk1, aq[rb][1], sc[rb][j], 0, 0, 0);
        }
      }
      // ---- exp2 + causal mask + PACKED P write (one b64 per (rb,j)) ----
      const bool domask = (c == nch - 1) || (c == nch - 2);
      #pragma unroll
      for (int rb = 0; rb < 2; ++rb) {
        const int qg = q0 + rb * 16 + l16;     // this lane's q-row
        #pragma unroll
        for (int j = 0; j < 4; ++j) {
          float pv[4];
          #pragma unroll
          for (int r = 0; r < 4; ++r) {
            float p = __builtin_amdgcn_exp2f(sc[rb][j][r]);
            if (domask) {
              if (s0 + j * 16 + quad * 4 + r > qg) p = 0.f;
            }
            lr[rb] += p;
            pv[r] = p;
          }
          ushort4 w;
          w.x = f2bf(pv[0]); w.y = f2bf(pv[1]); w.z = f2bf(pv[2]); w.w = f2bf(pv[3]);
          *(ushort4*)&lP[wave][rb * 16 + l16][j * 16 + quad * 4] = w;
        }
      }
      __builtin_amdgcn_wave_barrier();
      bf16x8 aP[2][2];                         // P fragments (now B-operand); same addrs
      #pragma unroll
      for (int rb = 0; rb < 2; ++rb)
        #pragma unroll
        for (int hh = 0; hh < 2; ++hh)
          aP[rb][hh] = ldb8(&lP[wave][rb * 16 + l16][hh * 32 + quad * 8]);
      __builtin_amdgcn_wave_barrier();
      // ---- PV (swapped: V as arg0) -> o[rb][nb][r] = O[q=rb*16+l16][d=nb*16+quad*4+r]
      #pragma unroll
      for (int nb = 0; nb < 4; ++nb) {
        const int d = nb * 16 + l16;
        bf16x8 bV0 = ldb8(Vb + d * 64 + ((quad ^ sw) << 3));
        bf16x8 bV1 = ldb8(Vb + d * 64 + (((4 + quad) ^ sw) << 3));
        #pragma unroll
        for (int rb = 0; rb < 2; ++rb) {
          o[rb][nb] = __builtin_amdgcn_mfma_f32_16x16x32_bf16(bV0, aP[rb][0], o[rb][nb], 0, 0, 0);
          o[rb][nb] = __builtin_amdgcn_mfma_f32_16x16x32_bf16(bV1, aP[rb][1], o[rb][nb], 0, 0, 0);
        }
      }
    }

    // epilogue: reduce lr over the 4 quads (lanes l16, l16+16, l16+32, l16+48),
    // normalize, packed 8B stores (4 consecutive d per lane)
    #pragma unroll
    for (int rb = 0; rb < 2; ++rb) {
      lr[rb] += __shfl_xor(lr[rb], 16, 64);
      lr[rb] += __shfl_xor(lr[rb], 32, 64);
      const float inv = 1.0f / lr[rb];
      const int t = q0 + rb * 16 + l16;
      #pragma unroll
      for (int nb = 0; nb < 4; ++nb) {
        ushort4 w;
        w.x = f2bf(o[rb][nb][0] * inv);
        w.y = f2bf(o[rb][nb][1] * inv);
        w.z = f2bf(o[rb][nb][2] * inv);
        w.w = f2bf(o[rb][nb][3] * inv);
        *(ushort4*)&ao[((size_t)(b * T_ + t) * H_ + h) * D_ + nb * 16 + quad * 4] = w;
      }
    }
  }
}

// ---------------- launch ----------------

extern "C" void kernel_launch(void* const* d_in, const int* in_sizes, int n_in,
                              void* d_out, int out_size, void* d_ws, size_t ws_size,
                              hipStream_t stream) {
  const float* x  = (const float*)d_in[0];
  const float* Wq = (const float*)d_in[1];
  const float* Wk = (const float*)d_in[2];
  const float* Wv = (const float*)d_in[3];
  const float* Wo = (const float*)d_in[4];
  float* out = (float*)d_out;

  char* ws = (char*)d_ws;
  unsigned short* xb   = (unsigned short*)(ws + 0);          // 16 MiB: x bf16 [8192,1024]
  unsigned short* wT   = (unsigned short*)(ws + 16777216);   //  6 MiB: [3,H,D,E] bf16
  unsigned short* woT  = (unsigned short*)(ws + 23068672);   //  2 MiB: [E,HD] bf16
  unsigned short* qb   = (unsigned short*)(ws + 25165824);   // 16 MiB: q [B,H,T,D] (pre-scaled)
  unsigned short* kb   = (unsigned short*)(ws + 41943040);   // 16 MiB: k [B,H,T,D]
  unsigned short* vTb  = (unsigned short*)(ws + 58720256);   // 16 MiB: v^T [B,H,D,T]
  unsigned short* aob  = (unsigned short*)(ws + 75497472);   // 16 MiB: attn out [B,T,H,D]
  // total: 92,274,688 bytes

  prep_k<<<dim3(3072), dim3(256), 0, stream>>>(x, Wq, Wk, Wv, Wo, xb, wT, woT);
  qkv_gemm_k<<<dim3(BT_ / 128, 3072 / 128), dim3(256), 0, stream>>>(xb, wT, qb, kb, vTb);
  attn_k<<<dim3(512), dim3(256), 0, stream>>>(qb, kb, vTb, aob);
  proj_k<<<dim3(BT_ / 128, E_ / 128), dim3(256), 0, stream>>>(aob, woT, out);
}